// Round 3
// baseline (587.602 us; speedup 1.0000x reference)
//
#include <hip/hip_runtime.h>

#define T_LEN 2048
#define HID   25
#define LOG2E 1.4426950408889634f

// may_alias vector for the LDS h-row readback (written as scalar float):
// without it, TBAA licenses hoisting the read above the publish (R3/R7 bug).
typedef float vf4 __attribute__((vector_size(16), may_alias));
typedef float f2  __attribute__((ext_vector_type(2)));

__device__ __forceinline__ float fast_rcp(float x) { return __builtin_amdgcn_rcpf(x); }
__device__ __forceinline__ float fast_exp2(float x) { return __builtin_amdgcn_exp2f(x); }

// R14. R12/R13's hand-rolled v_permlane32_swap asm produced two DIFFERENT
// wrong answers for the two possible return operands -- under any consistent
// semantics one of them had to be right, so the inline asm itself (dead-def
// register allocation) is untrustworthy. Restructure to need only ONE
// cross-half exchange and do it with __shfl_xor (compiler-correct ds_bpermute).
//
// Gate split (PyTorch order i,f,g,o):
//   lanes  0..24 (u)    own gates (i, g):  p = sig(i) * tanh(g)  -- all local
//   lanes 32..56 (32+u) own gates (f, o):  run the c/h chain:
//        c = fmaf(sig(f), c, p_from_lower);  h = sig(o) * tanh(c)
// One fp32 crosses per step: p, via __shfl_xor(p, 32, 64) (direction-agnostic).
// Upper half publishes h (bijection slots) + hist; lower half parks.
// 1 chain/wave, 2 waves/SIMD: per-wave serial issue per step ~halves vs the
// 546 us champion (24 pk_fma vs 48, 4 trans vs 10), sibling wave fills the
// LDS round-trip + transcendental latency that was exposed at 1 wave/SIMD
// (VALUBusy 67% -> ~210 stall cyc/step).
// Numerics bit-identical to the champion: same (k,k+12) pk-pairing, same
// acc.x + fmaf(h24,...) tail, same exp2-domain activations, same
// mul-then-fmaf c update, same y-dot order. Values only move between lanes.

__global__ __attribute__((amdgpu_flat_work_group_size(256, 256),
                          amdgpu_waves_per_eu(2, 2)))
void lstm_fused(
    const float* __restrict__ x,        // [B, T, 1]
    const float* __restrict__ w_ih,     // [100, 1]
    const float* __restrict__ w_hh,     // [100, 25]
    const float* __restrict__ b_ih,     // [100]
    const float* __restrict__ b_hh,     // [100]
    const float* __restrict__ w_dense,  // [1, 25]
    const float* __restrict__ b_dense,  // [1]
    float* __restrict__ out)            // [B, T, 1]
{
    const int tid = threadIdx.x;
    const int l   = tid & 63;            // lane in wave
    const int u   = l & 31;              // unit slot within half
    const int hh  = l >> 5;              // 0 -> gates (i,g); 1 -> gates (f,o)
    const int w   = tid >> 6;            // wave index in block, 0..3
    const int b   = blockIdx.x * 4 + w;  // chain (batch element)
    const bool act = u < HID;

    // Broadcast row per chain, 64 slots. UPPER lanes publish h: lane 32+m
    // (m<12) -> slot 2m, lane 32+12+m -> slot 2m+1, lane 32+24 -> slot 24,
    // upper junk (u=25..31) -> slot u. LOWER lanes park at slot 32+l.
    // Interleave [h0,h12,h1,h13,...,h11,h23,h24] so the b128 readback yields
    // register-aligned (h_k, h_{k+12}) pairs with no repack movs.
    __shared__ __align__(16) float hbuf[4][64];
    // h history for batched y: 64 steps x 65 floats (odd stride -> the
    // lane-strided read in the y phase is conflict-free). Upper lane 32+u
    // writes col u (real for u<25); lower lane l parks at col 32+l.
    __shared__ float hist[4][64][65];

    const float si = -LOG2E, sg = 2.f * LOG2E;

    // This lane's two gate rows:
    //   lower: rowA = u        (i, scale si), rowB = 2*HID+u (g, scale sg)
    //   upper: rowA = HID+u    (f, scale si), rowB = 3*HID+u (o, scale si)
    const int   rowA = hh ? (HID + u)     : u;
    const int   rowB = hh ? (3 * HID + u) : (2 * HID + u);
    const float scB  = hh ? si : sg;

    // ---- recurrent weights as (k, k+12) pairs, pre-scaled into exp2 domain ----
    f2 wA2[12], wB2[12];
#pragma unroll
    for (int m = 0; m < 12; ++m) {
        wA2[m] = act ? f2{si  * w_hh[rowA * HID + m], si  * w_hh[rowA * HID + m + 12]} : f2{0.f, 0.f};
        wB2[m] = act ? f2{scB * w_hh[rowB * HID + m], scB * w_hh[rowB * HID + m + 12]} : f2{0.f, 0.f};
    }
    const float wA24 = act ? si  * w_hh[rowA * HID + 24] : 0.f;
    const float wB24 = act ? scB * w_hh[rowB * HID + 24] : 0.f;
    const float bA   = act ? si  * (b_ih[rowA] + b_hh[rowA]) : 0.f;
    const float bB   = act ? scB * (b_ih[rowB] + b_hh[rowB]) : 0.f;
    const float wxA  = act ? si  * w_ih[rowA] : 0.f;
    const float wxB  = act ? scB * w_ih[rowB] : 0.f;
    const float bd   = b_dense[0];

    // dense weights (wave-uniform loads -> SGPRs)
    float wdv[HID];
#pragma unroll
    for (int i = 0; i < HID; ++i) wdv[i] = w_dense[i];

    // h0 = 0 (all 64 slots)
    hbuf[w][l] = 0.f;

    // publish slot: full-wave bijection (upper active -> interleaved 0..24,
    // upper junk -> 25..31, lower -> 32..63). 64 distinct slots, 2 lanes/bank.
    const int slot = hh ? ((u < 12) ? 2 * u : (u < 24) ? 2 * u - 23 : u)
                        : (l + 32);
    float* hwr = &hbuf[w][slot];
    const vf4* r4 = (const vf4*)&hbuf[w][0];
    const float* hbF = &hbuf[w][0];

    // hist column: upper writes u (real for u<25), lower parks at 32+l.
    const int hcol = hh ? u : (32 + l);

    const float4* __restrict__ xp = (const float4*)(x + (size_t)b * T_LEN);
    float* __restrict__ orow = out + (size_t)b * T_LEN;

    // h state as 12 register-aligned pairs (h_m, h_{m+12}) + h24
    f2 hp[12];
#pragma unroll
    for (int m = 0; m < 12; ++m) hp[m] = f2{0.f, 0.f};
    float h24 = 0.f;

    float c = 0.f;
    float4 xcur = xp[0];

    for (int it = 0; it < T_LEN / 4; ++it) {
        const int nx = (it + 1 < T_LEN / 4) ? it + 1 : it;
        float4 xnext = xp[nx];  // issued ~4 steps ahead of use
        float xs[4] = {xcur.x, xcur.y, xcur.z, xcur.w};

#pragma unroll
        for (int s = 0; s < 4; ++s) {
            const float xv = xs[s];
            const int t = 4 * it + s;

            // two gate pre-activations via v_pk_fma_f32; acc.x = k=0..11
            // accumulator, acc.y = k=12..23; h24 scalar-fma last; final
            // add acc.x + acc.y -- bit-identical order to the champion.
            f2 accA = f2{fmaf(xv, wxA, bA), 0.f};
            f2 accB = f2{fmaf(xv, wxB, bB), 0.f};
#pragma unroll
            for (int m = 0; m < 12; ++m) {
                const f2 h = hp[m];
                accA = __builtin_elementwise_fma(h, wA2[m], accA);
                accB = __builtin_elementwise_fma(h, wB2[m], accB);
            }
            const float aA = accA.x + fmaf(h24, wA24, accA.y);
            const float aB = accB.x + fmaf(h24, wB24, accB.y);

            // lower: rA = sig(i), tB = tanh(g);  upper: rA = sig(f), rB = sig(o)
            const float rA = fast_rcp(1.f + fast_exp2(aA));
            const float rB = fast_rcp(1.f + fast_exp2(aB));
            const float tB = fmaf(-2.f, rB, 1.f);

            // p: lower = sig(i)*tanh(g) (the real payload); upper = junk.
            const float p  = rA * tB;
            const float pX = __shfl_xor(p, 32, 64);  // partner's p (exact move)

            // c/h chain (meaningful on UPPER lanes: rA=sig(f), rB=sig(o),
            // pX = sig(i)*tanh(g) from the lower partner; lower lanes compute
            // bounded garbage that parks in unread slots)
            c = fmaf(rA, c, pX);               // == fmaf(sF, c, sI*tG)
            const float tC = fmaf(-2.f, fast_rcp(1.f + fast_exp2(2.f * LOG2E * c)), 1.f);
            const float hn = rB * tC;          // == sO * tanh(c)

            // ---- ordered publish -> readback (fences compile-time only;
            // same-wave DS ops execute in order on HW) ----
            *hwr = hn;                       // bijection slot (upper = real h)
            hist[w][t & 63][hcol] = hn;      // upper -> cols 0..24 real
            __asm__ __volatile__("" ::: "memory");
            {
                vf4 a0 = r4[0], a1 = r4[1], a2 = r4[2];
                vf4 a3 = r4[3], a4 = r4[4], a5 = r4[5];
                hp[0]  = f2{a0[0], a0[1]}; hp[1]  = f2{a0[2], a0[3]};
                hp[2]  = f2{a1[0], a1[1]}; hp[3]  = f2{a1[2], a1[3]};
                hp[4]  = f2{a2[0], a2[1]}; hp[5]  = f2{a2[2], a2[3]};
                hp[6]  = f2{a3[0], a3[1]}; hp[7]  = f2{a3[2], a3[3]};
                hp[8]  = f2{a4[0], a4[1]}; hp[9]  = f2{a4[2], a4[3]};
                hp[10] = f2{a5[0], a5[1]}; hp[11] = f2{a5[2], a5[3]};
                h24 = hbF[24];
            }
            __asm__ __volatile__("" ::: "memory");

            // batched y: every 64 steps lane l computes y[t0+l] (full 25-sum,
            // hist reads conflict-free by stride-65), all 64 lanes store.
            if ((t & 63) == 63) {
                const float* hrow = &hist[w][l][0];   // row for t' = t0 + l
                float ys = 0.f;
#pragma unroll
                for (int i = 0; i < HID; ++i)
                    ys = fmaf(hrow[i], wdv[i], ys);
                orow[(t & ~63) + l] = ys + bd;        // 256 B coalesced
            }
        }
        xcur = xnext;
    }
}

extern "C" void kernel_launch(void* const* d_in, const int* in_sizes, int n_in,
                              void* d_out, int out_size, void* d_ws, size_t ws_size,
                              hipStream_t stream) {
    const float* x       = (const float*)d_in[0];
    const float* w_ih    = (const float*)d_in[1];
    const float* w_hh    = (const float*)d_in[2];
    const float* b_ih    = (const float*)d_in[3];
    const float* b_hh    = (const float*)d_in[4];
    const float* w_dense = (const float*)d_in[5];
    const float* b_dense = (const float*)d_in[6];
    float* out = (float*)d_out;

    // 2048 chains, one per wave: 512 blocks x 256 threads -> 2048 waves
    // = 2 waves/SIMD chip-wide (8 waves/CU, 2 blocks/CU at 67.6 KB LDS each).
    lstm_fused<<<dim3(512), dim3(256), 0, stream>>>(x, w_ih, w_hh, b_ih, b_hh,
                                                    w_dense, b_dense, out);
}

// Round 4
// 585.219 us; speedup vs baseline: 1.0041x; 1.0041x over previous
//
#include <hip/hip_runtime.h>

#define T_LEN 2048
#define HID   25
#define LOG2E 1.4426950408889634f

// may_alias vector for the LDS h-row readback (written as scalar float):
// without it, TBAA licenses hoisting the read above the publish (R3/R7 bug).
typedef float vf4 __attribute__((vector_size(16), may_alias));
typedef float f2  __attribute__((ext_vector_type(2)));

__device__ __forceinline__ float fast_rcp(float x) { return __builtin_amdgcn_rcpf(x); }
__device__ __forceinline__ float fast_exp2(float x) { return __builtin_amdgcn_exp2f(x); }

// R15 = R14 (correct, 600 us) + SIMD-slot phase skew.
//
// R14 post-mortem: wall/step 703 cyc = 483 combined issue (2 waves) + 220
// exposed stall (h-exchange LDS round trip ~130 + trans chains ~80 + shfl).
// The sibling wave filled NOTHING: both waves run the identical instruction
// cadence under round-robin arbitration -> they hit their LDS-wait windows
// simultaneously (phase lock). R11 (1 wave/SIMD): 430 + 210 = 640. Same stall.
//
// Fix: one-time ~384-cycle sleep for the wave in the ODD wave-slot of each
// SIMD (HW_ID[3:0] via s_getreg -- same mechanism as XCC_ID probing). The two
// co-resident waves are from different blocks with no mutual dependencies and
// identical cadence, so the anti-phase offset is neutrally stable. With
// anti-phase, one wave's issue burst lands in the other's stall window:
// wall/step -> max(combined issue ~480, issue+stall ~500) ~= 500 cyc.
// Purely a timing perturbation: numerics bit-identical (absmax 1.953e-3).
//
// Structure (R14): 2 gates/lane, 1 chain/wave, 2 waves/SIMD.
//   lanes  0..24 own gates (i, g): p = sig(i)*tanh(g)   (all local)
//   lanes 32..56 own gates (f, o): c = fma(sig(f), c, p); h = sig(o)*tanh(c)
// One fp32 crosses per step via __shfl_xor(p, 32, 64). Upper half publishes
// h (interleaved bijection slots) + hist; lower half parks in unread slots.
// Same (k,k+12) pk-pairing, acc.x + fmaf(h24,...) tail, exp2-domain
// activations, mul-then-fmaf c update, y-dot order as the 546 us champion.

__global__ __attribute__((amdgpu_flat_work_group_size(256, 256),
                          amdgpu_waves_per_eu(2, 2)))
void lstm_fused(
    const float* __restrict__ x,        // [B, T, 1]
    const float* __restrict__ w_ih,     // [100, 1]
    const float* __restrict__ w_hh,     // [100, 25]
    const float* __restrict__ b_ih,     // [100]
    const float* __restrict__ b_hh,     // [100]
    const float* __restrict__ w_dense,  // [1, 25]
    const float* __restrict__ b_dense,  // [1]
    float* __restrict__ out)            // [B, T, 1]
{
    const int tid = threadIdx.x;
    const int l   = tid & 63;            // lane in wave
    const int u   = l & 31;              // unit slot within half
    const int hh  = l >> 5;              // 0 -> gates (i,g); 1 -> gates (f,o)
    const int w   = tid >> 6;            // wave index in block, 0..3
    const int b   = blockIdx.x * 4 + w;  // chain (batch element)
    const bool act = u < HID;

    // Broadcast row per chain, 64 slots. UPPER lanes publish h: lane 32+m
    // (m<12) -> slot 2m, lane 32+12+m -> slot 2m+1, lane 32+24 -> slot 24,
    // upper junk (u=25..31) -> slot u. LOWER lanes park at slot 32+l.
    // Interleave [h0,h12,h1,h13,...,h11,h23,h24] so the b128 readback yields
    // register-aligned (h_k, h_{k+12}) pairs with no repack movs.
    __shared__ __align__(16) float hbuf[4][64];
    // h history for batched y: 64 steps x 65 floats (odd stride -> the
    // lane-strided read in the y phase is conflict-free). Upper lane 32+u
    // writes col u (real for u<25); lower lane l parks at col 32+l.
    __shared__ float hist[4][64][65];

    const float si = -LOG2E, sg = 2.f * LOG2E;

    // This lane's two gate rows:
    //   lower: rowA = u        (i, scale si), rowB = 2*HID+u (g, scale sg)
    //   upper: rowA = HID+u    (f, scale si), rowB = 3*HID+u (o, scale si)
    const int   rowA = hh ? (HID + u)     : u;
    const int   rowB = hh ? (3 * HID + u) : (2 * HID + u);
    const float scB  = hh ? si : sg;

    // ---- recurrent weights as (k, k+12) pairs, pre-scaled into exp2 domain ----
    f2 wA2[12], wB2[12];
#pragma unroll
    for (int m = 0; m < 12; ++m) {
        wA2[m] = act ? f2{si  * w_hh[rowA * HID + m], si  * w_hh[rowA * HID + m + 12]} : f2{0.f, 0.f};
        wB2[m] = act ? f2{scB * w_hh[rowB * HID + m], scB * w_hh[rowB * HID + m + 12]} : f2{0.f, 0.f};
    }
    const float wA24 = act ? si  * w_hh[rowA * HID + 24] : 0.f;
    const float wB24 = act ? scB * w_hh[rowB * HID + 24] : 0.f;
    const float bA   = act ? si  * (b_ih[rowA] + b_hh[rowA]) : 0.f;
    const float bB   = act ? scB * (b_ih[rowB] + b_hh[rowB]) : 0.f;
    const float wxA  = act ? si  * w_ih[rowA] : 0.f;
    const float wxB  = act ? scB * w_ih[rowB] : 0.f;
    const float bd   = b_dense[0];

    // dense weights (wave-uniform loads -> SGPRs)
    float wdv[HID];
#pragma unroll
    for (int i = 0; i < HID; ++i) wdv[i] = w_dense[i];

    // h0 = 0 (all 64 slots)
    hbuf[w][l] = 0.f;

    // publish slot: full-wave bijection (upper active -> interleaved 0..24,
    // upper junk -> 25..31, lower -> 32..63). 64 distinct slots, 2 lanes/bank.
    const int slot = hh ? ((u < 12) ? 2 * u : (u < 24) ? 2 * u - 23 : u)
                        : (l + 32);
    float* hwr = &hbuf[w][slot];
    const vf4* r4 = (const vf4*)&hbuf[w][0];
    const float* hbF = &hbuf[w][0];

    // hist column: upper writes u (real for u<25), lower parks at 32+l.
    const int hcol = hh ? u : (32 + l);

    const float4* __restrict__ xp = (const float4*)(x + (size_t)b * T_LEN);
    float* __restrict__ orow = out + (size_t)b * T_LEN;

    // h state as 12 register-aligned pairs (h_m, h_{m+12}) + h24
    f2 hp[12];
#pragma unroll
    for (int m = 0; m < 12; ++m) hp[m] = f2{0.f, 0.f};
    float h24 = 0.f;

    float c = 0.f;
    float4 xcur = xp[0];

    // ---- phase skew: anti-phase the two waves sharing a SIMD ----
    // HW_ID[3:0] = wave slot within SIMD (hwreg id=4, offset=0, size=4 ->
    // imm = 4 | (0<<6) | (3<<11) = 6148). Odd slot sleeps ~6*64 = 384 cyc
    // (~half the 703-cyc step period) once. If HW_ID reads 0 for all waves,
    // this is a no-op and the kernel behaves exactly like R14.
    {
        const unsigned wslot = __builtin_amdgcn_s_getreg(6148);
        if (wslot & 1) __builtin_amdgcn_s_sleep(6);
    }

    for (int it = 0; it < T_LEN / 4; ++it) {
        const int nx = (it + 1 < T_LEN / 4) ? it + 1 : it;
        float4 xnext = xp[nx];  // issued ~4 steps ahead of use
        float xs[4] = {xcur.x, xcur.y, xcur.z, xcur.w};

#pragma unroll
        for (int s = 0; s < 4; ++s) {
            const float xv = xs[s];
            const int t = 4 * it + s;

            // two gate pre-activations via v_pk_fma_f32; acc.x = k=0..11
            // accumulator, acc.y = k=12..23; h24 scalar-fma last; final
            // add acc.x + acc.y -- bit-identical order to the champion.
            f2 accA = f2{fmaf(xv, wxA, bA), 0.f};
            f2 accB = f2{fmaf(xv, wxB, bB), 0.f};
#pragma unroll
            for (int m = 0; m < 12; ++m) {
                const f2 h = hp[m];
                accA = __builtin_elementwise_fma(h, wA2[m], accA);
                accB = __builtin_elementwise_fma(h, wB2[m], accB);
            }
            const float aA = accA.x + fmaf(h24, wA24, accA.y);
            const float aB = accB.x + fmaf(h24, wB24, accB.y);

            // lower: rA = sig(i), tB = tanh(g);  upper: rA = sig(f), rB = sig(o)
            const float rA = fast_rcp(1.f + fast_exp2(aA));
            const float rB = fast_rcp(1.f + fast_exp2(aB));
            const float tB = fmaf(-2.f, rB, 1.f);

            // p: lower = sig(i)*tanh(g) (the real payload); upper = junk.
            const float p  = rA * tB;
            const float pX = __shfl_xor(p, 32, 64);  // partner's p (exact move)

            // c/h chain (meaningful on UPPER lanes: rA=sig(f), rB=sig(o),
            // pX = sig(i)*tanh(g) from the lower partner; lower lanes compute
            // bounded garbage that parks in unread slots)
            c = fmaf(rA, c, pX);               // == fmaf(sF, c, sI*tG)
            const float tC = fmaf(-2.f, fast_rcp(1.f + fast_exp2(2.f * LOG2E * c)), 1.f);
            const float hn = rB * tC;          // == sO * tanh(c)

            // ---- ordered publish -> readback (fences compile-time only;
            // same-wave DS ops execute in order on HW) ----
            *hwr = hn;                       // bijection slot (upper = real h)
            hist[w][t & 63][hcol] = hn;      // upper -> cols 0..24 real
            __asm__ __volatile__("" ::: "memory");
            {
                vf4 a0 = r4[0], a1 = r4[1], a2 = r4[2];
                vf4 a3 = r4[3], a4 = r4[4], a5 = r4[5];
                hp[0]  = f2{a0[0], a0[1]}; hp[1]  = f2{a0[2], a0[3]};
                hp[2]  = f2{a1[0], a1[1]}; hp[3]  = f2{a1[2], a1[3]};
                hp[4]  = f2{a2[0], a2[1]}; hp[5]  = f2{a2[2], a2[3]};
                hp[6]  = f2{a3[0], a3[1]}; hp[7]  = f2{a3[2], a3[3]};
                hp[8]  = f2{a4[0], a4[1]}; hp[9]  = f2{a4[2], a4[3]};
                hp[10] = f2{a5[0], a5[1]}; hp[11] = f2{a5[2], a5[3]};
                h24 = hbF[24];
            }
            __asm__ __volatile__("" ::: "memory");

            // batched y: every 64 steps lane l computes y[t0+l] (full 25-sum,
            // hist reads conflict-free by stride-65), all 64 lanes store.
            if ((t & 63) == 63) {
                const float* hrow = &hist[w][l][0];   // row for t' = t0 + l
                float ys = 0.f;
#pragma unroll
                for (int i = 0; i < HID; ++i)
                    ys = fmaf(hrow[i], wdv[i], ys);
                orow[(t & ~63) + l] = ys + bd;        // 256 B coalesced
            }
        }
        xcur = xnext;
    }
}

extern "C" void kernel_launch(void* const* d_in, const int* in_sizes, int n_in,
                              void* d_out, int out_size, void* d_ws, size_t ws_size,
                              hipStream_t stream) {
    const float* x       = (const float*)d_in[0];
    const float* w_ih    = (const float*)d_in[1];
    const float* w_hh    = (const float*)d_in[2];
    const float* b_ih    = (const float*)d_in[3];
    const float* b_hh    = (const float*)d_in[4];
    const float* w_dense = (const float*)d_in[5];
    const float* b_dense = (const float*)d_in[6];
    float* out = (float*)d_out;

    // 2048 chains, one per wave: 512 blocks x 256 threads -> 2048 waves
    // = 2 waves/SIMD chip-wide (8 waves/CU, 2 blocks/CU at 67.6 KB LDS each).
    lstm_fused<<<dim3(512), dim3(256), 0, stream>>>(x, w_ih, w_hh, b_ih, b_hh,
                                                    w_dense, b_dense, out);
}